// Round 5
// baseline (367.674 us; speedup 1.0000x reference)
//
#include <hip/hip_runtime.h>
#include <hip/hip_bf16.h>
#include <float.h>

#define NN 2048
#define HH 16
#define DDIM 64
#define QB 32   // q-rows per block = 2 waves x 16 rows
#define KB 64

typedef __bf16 bf16x8 __attribute__((ext_vector_type(8)));
typedef __bf16 bf16x4 __attribute__((ext_vector_type(4)));
typedef float f32x4 __attribute__((ext_vector_type(4)));

// Raw barrier: LDS-writes visible; outstanding GLOBAL prefetch loads stay in flight.
__device__ __forceinline__ void barw() {
  __builtin_amdgcn_sched_barrier(0);
  asm volatile("s_waitcnt lgkmcnt(0)" ::: "memory");
  __builtin_amdgcn_s_barrier();
  __builtin_amdgcn_sched_barrier(0);
}

__device__ __forceinline__ unsigned pack2(float a, float b) {
  union { __bf16 h[2]; unsigned u; } x;
  x.h[0] = (__bf16)a; x.h[1] = (__bf16)b;
  return x.u;
}

// R5: 128-thread / 2-wave blocks, QB=32 -> grid 1024 = 4 independent block
// streams per CU (latency hiding + 4x in-flight HBM bytes). Swapped-QK^T
// row-owning waves as R4; prev/bias prefetch issue moved AFTER softmax
// consumption (no shadow copies -> VGPR budget for 4 blocks/CU).
__global__ __launch_bounds__(128, 2) void attend_fused(
    const float* __restrict__ qg, const float* __restrict__ kg,
    const float* __restrict__ vg, const unsigned int* __restrict__ maskw,
    const float* __restrict__ biasg, const float* __restrict__ prevg,
    float* __restrict__ outg)
{
  __shared__ char  ksh[KB * 128]   __attribute__((aligned(16))); // [kv][d] bf16, XOR-swizzled
  __shared__ char  vsh[DDIM * 128] __attribute__((aligned(16))); // [d][kv] bf16, XOR-swizzled
  __shared__ float vmean_s[DDIM];

  const int t    = threadIdx.x;
  const int lane = t & 63;
  const int w    = t >> 6;      // 0..1
  const int x    = blockIdx.x;  // 0..63
  const int h    = blockIdx.y;
  // causal balance: CU slot rounds {c, c+256, c+512, c+768}; +512 flips h<8 ->
  // complementary qt (sum of tile counts = 33) on the same CU.
  const int qt   = (h < 8) ? x : (63 - x);
  const int qrow0 = qt * QB;

  // --- mask element-width detection: 4-byte (int/float bool) vs 1-byte ---
  unsigned int mw0 = maskw[t];
  unsigned int mw1 = maskw[t + 128];
  const int ok0 = (mw0 == 0u || mw0 == 1u || mw0 == 0x3F800000u) &&
                  (mw1 == 0u || mw1 == 1u || mw1 == 0x3F800000u);
  const int mask4 = __syncthreads_and(ok0);

  const int llo = lane & 15;
  const int lhi = lane >> 4;
  const int qrow_g = qrow0 + w * 16 + llo;   // this lane's q-row

  // --- Q fragments (B operand), scale 1/8 folded in ---
  bf16x8 aq[2];
  {
    const float* qp = qg + ((size_t)(h * NN + qrow_g)) * DDIM + lhi * 8;
#pragma unroll
    for (int ks = 0; ks < 2; ++ks) {
      float4 f0 = *(const float4*)(qp + ks * 32);
      float4 f1 = *(const float4*)(qp + ks * 32 + 4);
      bf16x8 a;
      a[0] = (__bf16)(f0.x * 0.125f); a[1] = (__bf16)(f0.y * 0.125f);
      a[2] = (__bf16)(f0.z * 0.125f); a[3] = (__bf16)(f0.w * 0.125f);
      a[4] = (__bf16)(f1.x * 0.125f); a[5] = (__bf16)(f1.y * 0.125f);
      a[6] = (__bf16)(f1.z * 0.125f); a[7] = (__bf16)(f1.w * 0.125f);
      aq[ks] = a;
    }
  }

  f32x4 oacc[4];   // O^T frags: oacc[df][r] = O[q=llo-row][d=df*16+lhi*4+r]
#pragma unroll
  for (int i = 0; i < 4; ++i) { f32x4 z = {0.f, 0.f, 0.f, 0.f}; oacc[i] = z; }
  float m_r = -FLT_MAX, l_r = 0.f;

  // ---- prefetch registers ----
  float4 kpre[8], vpre[8];          // 64x64 K and V tile staged by 128 threads
  float4 ppre[4], bpre[4];
  uint4  mpre[4];

  auto issueKV = [&](int kv0) {
#pragma unroll
    for (int e = 0; e < 8; ++e) {
      const int f4  = t + e * 128;      // 0..1023 float4s
      const int row = f4 >> 4;
      const int cb  = (f4 & 15) * 4;
      const size_t gofs = ((size_t)(h * NN + kv0 + row)) * DDIM + cb;
      kpre[e] = *(const float4*)(kg + gofs);
      vpre[e] = *(const float4*)(vg + gofs);
    }
  };
  auto issuePB = [&](int kv0) {
#pragma unroll
    for (int kf = 0; kf < 4; ++kf) {
      const int col = kv0 + kf * 16 + lhi * 4;
      const size_t base = ((size_t)(h * NN) + qrow_g) * NN + col;
      ppre[kf] = *(const float4*)(prevg + base);
      bpre[kf] = *(const float4*)(biasg + base);
      const size_t midx = (size_t)qrow_g * NN + col;
      if (mask4) {
        mpre[kf] = *(const uint4*)(maskw + midx);
      } else {
        mpre[kf].x = *(const unsigned int*)((const unsigned char*)maskw + midx);
      }
    }
  };

  const int Tq = (qt >> 1) + 1;
  issueKV(0);
  issuePB(0);

  for (int tt = 0; tt < Tq; ++tt) {
    const int kv0 = tt * KB;
    // ---- phase 1: stage K (row-major) and V (transposed), f32->bf16, swizzled ----
#pragma unroll
    for (int e = 0; e < 8; ++e) {
      const int f4  = t + e * 128;
      const int row = f4 >> 4;
      const int cb  = (f4 & 15) * 4;
      float4 kf = kpre[e];
      bf16x4 kb4;
      kb4[0] = (__bf16)kf.x; kb4[1] = (__bf16)kf.y;
      kb4[2] = (__bf16)kf.z; kb4[3] = (__bf16)kf.w;
      *(bf16x4*)(ksh + (((row << 7) + (cb << 1)) ^ ((row & 7) << 4))) = kb4;
      float4 vf = vpre[e];
      *(__bf16*)(vsh + ((((cb + 0) << 7) + (row << 1)) ^ (((cb + 0) & 7) << 4))) = (__bf16)vf.x;
      *(__bf16*)(vsh + ((((cb + 1) << 7) + (row << 1)) ^ (((cb + 1) & 7) << 4))) = (__bf16)vf.y;
      *(__bf16*)(vsh + ((((cb + 2) << 7) + (row << 1)) ^ (((cb + 2) & 7) << 4))) = (__bf16)vf.z;
      *(__bf16*)(vsh + ((((cb + 3) << 7) + (row << 1)) ^ (((cb + 3) & 7) << 4))) = (__bf16)vf.w;
    }
    // issue next tile's K/V now (regs consumed; loads fly across barriers)
    if (tt + 1 < Tq) issueKV(kv0 + KB);
    barw();

    // ---- QK^T swapped: S^T[kv][q], each lane: q=llo-row, 16 kv values ----
    f32x4 s[4];
#pragma unroll
    for (int kf = 0; kf < 4; ++kf) { f32x4 z = {0.f, 0.f, 0.f, 0.f}; s[kf] = z; }
#pragma unroll
    for (int ks = 0; ks < 2; ++ks) {
#pragma unroll
      for (int kf = 0; kf < 4; ++kf) {
        const int kvr = kf * 16 + llo;
        bf16x8 ak = *(const bf16x8*)(ksh + (((kvr << 7) + ((ks * 32 + lhi * 8) << 1)) ^ ((kvr & 7) << 4)));
        s[kf] = __builtin_amdgcn_mfma_f32_16x16x32_bf16(ak, aq[ks], s[kf], 0, 0, 0);
      }
    }

    // ---- softmax, fully in-register (row = q = llo; 4 lanes/row via xor16/32) ----
    float p[4][4];
    float pmax = -FLT_MAX;
#pragma unroll
    for (int kf = 0; kf < 4; ++kf) {
      float pa[4] = {ppre[kf].x, ppre[kf].y, ppre[kf].z, ppre[kf].w};
      float ba[4] = {bpre[kf].x, bpre[kf].y, bpre[kf].z, bpre[kf].w};
      unsigned mb[4];
      if (mask4) { mb[0] = mpre[kf].x; mb[1] = mpre[kf].y; mb[2] = mpre[kf].z; mb[3] = mpre[kf].w; }
      else {
        mb[0] = mpre[kf].x & 0xffu; mb[1] = (mpre[kf].x >> 8) & 0xffu;
        mb[2] = (mpre[kf].x >> 16) & 0xffu; mb[3] = mpre[kf].x >> 24;
      }
#pragma unroll
      for (int r = 0; r < 4; ++r) {
        const int j = kv0 + kf * 16 + lhi * 4 + r;
        float sv = s[kf][r] + pa[r] + ba[r];
        if (j > qrow_g || mb[r] == 0u) sv = -FLT_MAX;
        p[kf][r] = sv;
        pmax = fmaxf(pmax, sv);
      }
    }
    // prev/bias/mask regs consumed -> issue next tile's (fly across barrier)
    if (tt + 1 < Tq) issuePB(kv0 + KB);
    pmax = fmaxf(pmax, __shfl_xor(pmax, 16));
    pmax = fmaxf(pmax, __shfl_xor(pmax, 32));
    const float mnew = fmaxf(m_r, pmax);
    const float resc = __expf(m_r - mnew);   // exp(0)=1 when both -FLT_MAX (finite)
    float psum = 0.f;
#pragma unroll
    for (int kf = 0; kf < 4; ++kf)
#pragma unroll
      for (int r = 0; r < 4; ++r) {
        float e = __expf(p[kf][r] - mnew);
        p[kf][r] = e;
        psum += e;
      }
    psum += __shfl_xor(psum, 16);
    psum += __shfl_xor(psum, 32);
    l_r = l_r * resc + psum;
    m_r = mnew;
#pragma unroll
    for (int df = 0; df < 4; ++df) {
      oacc[df][0] *= resc; oacc[df][1] *= resc;
      oacc[df][2] *= resc; oacc[df][3] *= resc;
    }

    // ---- pack P -> bf16 pairs; redistribute P^T into PV B-operand; PV MFMAs ----
    unsigned U[4][2];
#pragma unroll
    for (int kf = 0; kf < 4; ++kf) {
      U[kf][0] = pack2(p[kf][0], p[kf][1]);
      U[kf][1] = pack2(p[kf][2], p[kf][3]);
    }
#pragma unroll
    for (int ks = 0; ks < 2; ++ks) {
      unsigned bb[4];
#pragma unroll
      for (int m = 0; m < 4; ++m) {
        // dst lane needs kv u32-pair p = ks*16 + lhi*4 + m of its q-row.
        // src lane: same llo, lhi_src = (lhi&1)*2 + (m>>1); frag = 2ks + (lhi>>1); half = m&1.
        const int src = llo + ((((lhi & 1) << 1) + (m >> 1)) << 4);
        const int va = __shfl((int)U[2 * ks + 0][m & 1], src);
        const int vb = __shfl((int)U[2 * ks + 1][m & 1], src);
        bb[m] = (lhi >> 1) ? (unsigned)vb : (unsigned)va;
      }
      union { unsigned u[4]; bf16x8 v; } pb_;
      pb_.u[0] = bb[0]; pb_.u[1] = bb[1]; pb_.u[2] = bb[2]; pb_.u[3] = bb[3];
#pragma unroll
      for (int df = 0; df < 4; ++df) {
        const int dr = df * 16 + llo;
        bf16x8 vf = *(const bf16x8*)(vsh + (((dr << 7) + ((ks * 32 + lhi * 8) << 1)) ^ ((dr & 7) << 4)));
        oacc[df] = __builtin_amdgcn_mfma_f32_16x16x32_bf16(vf, pb_.v, oacc[df], 0, 0, 0);
      }
    }
    barw();   // all waves done reading ksh/vsh before next staging overwrite
  } // kv tiles

  // ---- epilogue: each wave owns its rows; no cross-wave combine ----
  const int anyNeed = __syncthreads_or(m_r == -FLT_MAX);
  if (anyNeed) {
    // fully-masked row: ref softmax uniform over ALL 2048 -> column mean of V
    if (t < DDIM) vmean_s[t] = 0.f;
    __syncthreads();
    {
      const int d = t & 63, part = t >> 6;   // part 0..1
      float sacc = 0.f;
      for (int j = part; j < NN; j += 2) sacc += vg[((size_t)(h * NN + j)) * DDIM + d];
      atomicAdd(&vmean_s[d], sacc);
    }
    __syncthreads();
    if (t < DDIM) vmean_s[t] *= (1.0f / (float)NN);
    __syncthreads();
  }
  const float invl = 1.0f / l_r;
  const bool dead = (m_r == -FLT_MAX);
#pragma unroll
  for (int df = 0; df < 4; ++df) {
    const int dbase = df * 16 + lhi * 4;
    float4 o;
    o.x = dead ? vmean_s[dbase + 0] : oacc[df][0] * invl;
    o.y = dead ? vmean_s[dbase + 1] : oacc[df][1] * invl;
    o.z = dead ? vmean_s[dbase + 2] : oacc[df][2] * invl;
    o.w = dead ? vmean_s[dbase + 3] : oacc[df][3] * invl;
    *(float4*)(outg + ((size_t)(h * NN) + qrow_g) * DDIM + dbase) = o;
  }
}

extern "C" void kernel_launch(void* const* d_in, const int* in_sizes, int n_in,
                              void* d_out, int out_size, void* d_ws, size_t ws_size,
                              hipStream_t stream) {
  (void)in_sizes; (void)n_in; (void)d_ws; (void)ws_size; (void)out_size;
  const float* q    = (const float*)d_in[0];
  const float* k    = (const float*)d_in[1];
  const float* v    = (const float*)d_in[2];
  const unsigned int* mask = (const unsigned int*)d_in[3];
  const float* bias = (const float*)d_in[4];
  const float* prev = (const float*)d_in[5];
  float* out = (float*)d_out;

  dim3 grid(64, HH);
  attend_fused<<<grid, 128, 0, stream>>>(q, k, v, mask, bias, prev, out);
}